// Round 8
// baseline (620.632 us; speedup 1.0000x reference)
//
#include <hip/hip_runtime.h>
#include <hip/hip_bf16.h>

// MultiExpertLoRALinear on MI355X.
// Round 8: GEMM with 3-slot LDS rotation -> genuinely-counted vmcnt (T4).
// R7's 2-slot version drained vmcnt(0) per tile (cooperative staging forces a
// full drain with <1 tile prefetch). 3 slots let tile t stage tile t+2, so the
// boundary wait is vmcnt(6) with t+2's loads IN FLIGHT across it (the m218
// mechanism). BM=256,BN=128: slot=48KB, 3 slots=144KB LDS. Epilogue reordered
// for 128B-contiguous stores (R7 WRITE_SIZE 185MB -> ~140).
// Pipeline:
//   convert_w3    : wh[o][KP] fp16 = [W_base | Bcat | 0]; vh[48][H] fp16.
//   router_fused5 : x -> fp16 (reg) -> xh main cols + z = x*vh^T via MFMA,
//                   16-wave in-block reduce, softmax, c cols + zero pad.
//   gemm          : fp16 MFMA GEMM [M, O, KP=4160], 256x128 tile, BK=64,
//                   8 waves (2Mx4N), 144 KiB LDS (3 slots), XOR-swizzle,
//                   global_load_lds, 2 phases/tile, vmcnt(6) boundary waits.

typedef _Float16 f16x8 __attribute__((ext_vector_type(8)));
typedef float    f32x4 __attribute__((ext_vector_type(4)));

constexpr int H  = 4096;
constexpr int O  = 4096;
constexpr int KP = 4160;   // 4096 + 32 (c cols) + 32 zero pad
constexpr int EA = 4;
constexpr float SCALING_F = 2.0f;  // alpha/rank

typedef const __attribute__((address_space(1))) void gvoid;
typedef __attribute__((address_space(3))) void svoid;

__device__ inline void gload16(const void* g, void* s) {
  __builtin_amdgcn_global_load_lds((gvoid*)g, (svoid*)s, 16, 0, 0);
}

// ---------------------------------------------------------------------------
// Kernel 1: build wh and vh. Block o < O: wh row o. Block O+j: vh row j.
// ---------------------------------------------------------------------------
__global__ __launch_bounds__(256) void convert_w3_kernel(
    const float* __restrict__ W, const float* __restrict__ lora_B,
    const float* __restrict__ lora_A, const float* __restrict__ router_W,
    const int* __restrict__ active, _Float16* __restrict__ wh,
    _Float16* __restrict__ vh) {
  const int bid = blockIdx.x;
  const int tid = threadIdx.x;
  if (bid < O) {
    const int o = bid;
    const float* wrow = W + (size_t)o * H;
    _Float16* dstrow = wh + (size_t)o * KP;
    for (int g = tid; g < 520; g += 256) {
      const int k = g * 8;
      float v[8];
      if (k < H) {
        float4 a = *(const float4*)(wrow + k), b = *(const float4*)(wrow + k + 4);
        v[0] = a.x; v[1] = a.y; v[2] = a.z; v[3] = a.w;
        v[4] = b.x; v[5] = b.y; v[6] = b.z; v[7] = b.w;
      } else if (k < H + 32) {
        const int e = (k - H) >> 3;
        const float* s = lora_B + ((size_t)active[e] * O + o) * 8;  // [E,O,r]
        float4 a = *(const float4*)s, b = *(const float4*)(s + 4);
        v[0] = a.x; v[1] = a.y; v[2] = a.z; v[3] = a.w;
        v[4] = b.x; v[5] = b.y; v[6] = b.z; v[7] = b.w;
      } else {
#pragma unroll
        for (int i = 0; i < 8; ++i) v[i] = 0.f;
      }
      f16x8 h;
#pragma unroll
      for (int i = 0; i < 8; ++i) h[i] = (_Float16)v[i];
      *(f16x8*)(dstrow + k) = h;
    }
  } else {
    const int j = bid - O;          // 0..47
    const float* src = nullptr;
    if (j < 32)      src = lora_A + (size_t)(active[j >> 3] * 8 + (j & 7)) * H;
    else if (j < 36) src = router_W + (size_t)active[j - 32] * H;
    _Float16* dstrow = vh + (size_t)j * H;
    for (int g = tid; g < 512; g += 256) {
      const int k = g * 8;
      f16x8 h;
      if (src) {
        float4 a = *(const float4*)(src + k), b = *(const float4*)(src + k + 4);
        h[0] = (_Float16)a.x; h[1] = (_Float16)a.y;
        h[2] = (_Float16)a.z; h[3] = (_Float16)a.w;
        h[4] = (_Float16)b.x; h[5] = (_Float16)b.y;
        h[6] = (_Float16)b.z; h[7] = (_Float16)b.w;
      } else {
#pragma unroll
        for (int i = 0; i < 8; ++i) h[i] = (_Float16)0.f;
      }
      *(f16x8*)(dstrow + k) = h;
    }
  }
}

// ---------------------------------------------------------------------------
// Kernel 2: fused convert_x + router + c-columns (unchanged from R5).
// ---------------------------------------------------------------------------
constexpr int RW5 = 16;   // waves per block

__global__ __launch_bounds__(1024) void router_fused5_kernel(
    const float* __restrict__ x, const _Float16* __restrict__ vh,
    const float* __restrict__ router_b, const float* __restrict__ prior,
    const int* __restrict__ active, _Float16* __restrict__ xh) {
  __shared__ float zred[RW5][16][48];   // 48 KB
  const int tid  = threadIdx.x;
  const int lane = tid & 63;
  const int w    = tid >> 6;            // 0..15
  const long t0  = (long)blockIdx.x * 16;
  const int r15  = lane & 15;
  const int kg   = lane >> 4;

  const float*    xp  = x  + (t0 + r15) * H  + w * 256 + kg * 8;
  _Float16*       xhp = xh + (t0 + r15) * KP + w * 256 + kg * 8;
  const _Float16* vp  = vh + (size_t)r15 * H + w * 256 + kg * 8;

  f32x4 acc[3];
  const f32x4 zero = {0.f, 0.f, 0.f, 0.f};
  acc[0] = zero; acc[1] = zero; acc[2] = zero;

#pragma unroll
  for (int c = 0; c < 8; ++c) {
    const int ko = c * 32;
    float4 v0 = *(const float4*)(xp + ko);
    float4 v1 = *(const float4*)(xp + ko + 4);
    f16x8 a;
    a[0] = (_Float16)v0.x; a[1] = (_Float16)v0.y;
    a[2] = (_Float16)v0.z; a[3] = (_Float16)v0.w;
    a[4] = (_Float16)v1.x; a[5] = (_Float16)v1.y;
    a[6] = (_Float16)v1.z; a[7] = (_Float16)v1.w;
    *(f16x8*)(xhp + ko) = a;
#pragma unroll
    for (int nf = 0; nf < 3; ++nf) {
      f16x8 b = *(const f16x8*)(vp + (size_t)nf * 16 * H + ko);
      acc[nf] = __builtin_amdgcn_mfma_f32_16x16x32_f16(a, b, acc[nf], 0, 0, 0);
    }
  }

  // scatter partials: C/D layout col=lane&15 (j), row=(lane>>4)*4+r (token)
#pragma unroll
  for (int nf = 0; nf < 3; ++nf)
#pragma unroll
    for (int r = 0; r < 4; ++r)
      zred[w][kg * 4 + r][nf * 16 + r15] = acc[nf][r];
  __syncthreads();

  // reduce 16 wave-partials: 768 slots, one per thread (tid < 768)
  float s = 0.f;
  int tt = 0, jj = 0;
  if (tid < 16 * 48) {
    tt = tid / 48; jj = tid % 48;
#pragma unroll
    for (int ww = 0; ww < RW5; ++ww) s += zred[ww][tt][jj];
  }
  __syncthreads();
  if (tid < 16 * 48) zred[0][tt][jj] = s;
  __syncthreads();

  // softmax + c-columns + zero pad: thread = (token tt, expert e)
  if (tid < 16 * EA) {
    const int t2 = tid >> 2, e = tid & 3;
    const float* zt = &zred[0][t2][0];
    float le[EA], mx = -1e30f;
#pragma unroll
    for (int e2 = 0; e2 < EA; ++e2) {
      const int ae = active[e2];
      le[e2] = logf(prior[ae] + 1e-12f) + zt[32 + e2] + router_b[ae];
      mx = fmaxf(mx, le[e2]);
    }
    float sum = 0.f;
#pragma unroll
    for (int e2 = 0; e2 < EA; ++e2) sum += expf(le[e2] - mx);
    const float a = expf(le[e] - mx) / sum * SCALING_F;
    f16x8 ch, zz;
#pragma unroll
    for (int r = 0; r < 8; ++r) {
      ch[r] = (_Float16)(a * zt[e * 8 + r]);
      zz[r] = (_Float16)0.f;
    }
    _Float16* xr = xh + (t0 + t2) * KP + H;
    *(f16x8*)(xr + e * 8) = ch;
    *(f16x8*)(xr + 32 + e * 8) = zz;
  }
}

// ---------------------------------------------------------------------------
// Kernel 3: fp16 MFMA GEMM, 256x128 tile, 3-slot rotation, counted vmcnt.
// 512 thr = 8 waves; wr=wave>>2 (M-half), wc=wave&3 (N-quarter); per-wave
// output 128x32 = 8 m-frags x 2 n-frags. LDS: 3 x (A 32KB + B 16KB) = 144 KiB.
// Per K-tile t (slot t%3), 2 phases q (m-half quadrant):
//   {12 ds_read_b128 (XOR-swizzled, 0-conflict-validated);
//    stage tile t+2 -> slot (t+2)%3 (q0: A halves 4 loads, q1: B 2 loads);
//    s_barrier; lgkmcnt(0)+sched_barrier; setprio(1); 16 MFMA; setprio(0);
//    q==1: vmcnt(6)  [t+1 landed; t+2's 6 loads REMAIN IN FLIGHT]; s_barrier}
// Slot race-freedom: slot (t+2)%3's previous reader is tile t-1, whose last
// reads completed before tile t began (trailing barrier). Lands-before-read:
// boundary vmcnt(6) + barrier guarantee t+1 fully in LDS for every wave.
// ---------------------------------------------------------------------------
constexpr int BM = 256, BN = 128, BK = 64, NT = KP / BK;  // 65 tiles

__global__ __launch_bounds__(512) void gemm_kernel(
    const _Float16* __restrict__ xh, const _Float16* __restrict__ wh,
    const float* __restrict__ b_base, float* __restrict__ out) {
  __shared__ _Float16 As[3][BM * BK];   // 3 x 32 KB
  __shared__ _Float16 Ws[3][BN * BK];   // 3 x 16 KB
  const int tid  = threadIdx.x;
  const int lane = tid & 63;
  const int wave = tid >> 6;            // 0..7
  const int bid  = (int)blockIdx.x;
  const int im = bid >> 5;              // 32 M-tiles
  const int in = bid & 31;              // 32 N-tiles
  const size_t trow0 = (size_t)im * BM;
  const size_t ocol0 = (size_t)in * BN;
  const int wr = wave >> 2;             // 0..1  M-half
  const int wc = wave & 3;              // 0..3  N-quarter (32 cols)
  const int r15 = lane & 15;
  const int kg  = lane >> 4;

  f32x4 acc[8][2];
  const f32x4 zero = {0.f, 0.f, 0.f, 0.f};
#pragma unroll
  for (int m = 0; m < 8; ++m)
#pragma unroll
    for (int n = 0; n < 2; ++n) acc[m][n] = zero;

  // stage A-half h (128 rows x 64 cols) of tile t into slot s: 2 gload16/thread
  auto stageA = [&](int s, int t, int h) {
#pragma unroll
    for (int i = 0; i < 2; ++i) {
      const int idx = tid + 512 * i;          // 0..1023
      const int row = idx >> 3;               // 0..127
      const int sg  = (idx & 7) ^ (row & 7);  // pre-swizzled source slot
      gload16(xh + (trow0 + h * 128 + row) * KP + t * 64 + sg * 8,
              &As[s][h * 8192 + idx * 8]);
    }
  };
  // stage B (128 rows x 64 cols): 2 gload16/thread
  auto stageB = [&](int s, int t) {
#pragma unroll
    for (int i = 0; i < 2; ++i) {
      const int idx = tid + 512 * i;
      const int row = idx >> 3;
      const int sg  = (idx & 7) ^ (row & 7);
      gload16(wh + (ocol0 + row) * KP + t * 64 + sg * 8, &Ws[s][idx * 8]);
    }
  };

  // prologue: tiles 0 and 1 (12 loads); wait until tile 0 landed (6 in flight)
  stageA(0, 0, 0); stageA(0, 0, 1); stageB(0, 0);
  stageA(1, 1, 0); stageA(1, 1, 1); stageB(1, 1);
  asm volatile("s_waitcnt vmcnt(6)" ::: "memory");
  __builtin_amdgcn_s_barrier();

  for (int t = 0; t < NT; ++t) {
    const int s  = t % 3;
    const int s2 = (t + 2) % 3;
    const _Float16* Ab = &As[s][0];
    const _Float16* Bb = &Ws[s][0];
#pragma unroll
    for (int q = 0; q < 2; ++q) {
      // 12 ds_read_b128: A m-frags (4m x 2kk) of half q, B n-frags (2n x 2kk)
      f16x8 af[4][2], bf[2][2];
#pragma unroll
      for (int m = 0; m < 4; ++m) {
        const int row = wr * 128 + (q * 4 + m) * 16 + r15;
#pragma unroll
        for (int kk = 0; kk < 2; ++kk) {
          const int slot = (kk * 4 + kg) ^ (row & 7);
          af[m][kk] = *(const f16x8*)(Ab + row * 64 + slot * 8);
        }
      }
#pragma unroll
      for (int n = 0; n < 2; ++n) {
        const int row = wc * 32 + n * 16 + r15;
#pragma unroll
        for (int kk = 0; kk < 2; ++kk) {
          const int slot = (kk * 4 + kg) ^ (row & 7);
          bf[n][kk] = *(const f16x8*)(Bb + row * 64 + slot * 8);
        }
      }
      // stage tile t+2 into slot s2 (its previous reader, tile t-1, is done)
      if (t + 2 < NT) {
        if (q == 0) { stageA(s2, t + 2, 0); stageA(s2, t + 2, 1); }
        else        { stageB(s2, t + 2); }
      }
      __builtin_amdgcn_s_barrier();
      asm volatile("s_waitcnt lgkmcnt(0)" ::: "memory");
      __builtin_amdgcn_sched_barrier(0);
      __builtin_amdgcn_s_setprio(1);
#pragma unroll
      for (int m = 0; m < 4; ++m)
#pragma unroll
        for (int n = 0; n < 2; ++n)
#pragma unroll
          for (int kk = 0; kk < 2; ++kk)
            acc[q * 4 + m][n] = __builtin_amdgcn_mfma_f32_16x16x32_f16(
                af[m][kk], bf[n][kk], acc[q * 4 + m][n], 0, 0, 0);
      __builtin_amdgcn_s_setprio(0);
      __builtin_amdgcn_sched_barrier(0);
      if (q == 1) {
        if (t < NT - 2)        // t+1 landed; t+2's 6 loads stay in flight
          asm volatile("s_waitcnt vmcnt(6)" ::: "memory");
        else if (t == NT - 2)  // final drain before last tile
          asm volatile("s_waitcnt vmcnt(0)" ::: "memory");
      }
      __builtin_amdgcn_s_barrier();
    }
  }

  // epilogue: C/D layout col=lane&15 (o), row=(lane>>4)*4+j (token).
  // n-inner store order -> each row's 2x64B stores are 128B-contiguous.
#pragma unroll
  for (int n = 0; n < 2; ++n) {
    // bias per column, hoisted
  }
  float bb[2];
#pragma unroll
  for (int n = 0; n < 2; ++n) bb[n] = b_base[ocol0 + wc * 32 + n * 16 + r15];
#pragma unroll
  for (int m = 0; m < 8; ++m) {
    const size_t row = trow0 + wr * 128 + m * 16 + kg * 4;
#pragma unroll
    for (int j = 0; j < 4; ++j) {
      float* orow = out + (row + j) * O + ocol0 + wc * 32 + r15;
#pragma unroll
      for (int n = 0; n < 2; ++n)
        orow[n * 16] = acc[m][n][j] + bb[n];
    }
  }
}

// ---------------------------------------------------------------------------
extern "C" void kernel_launch(void* const* d_in, const int* in_sizes, int n_in,
                              void* d_out, int out_size, void* d_ws, size_t ws_size,
                              hipStream_t stream) {
  const float* x        = (const float*)d_in[0];
  const float* W_base   = (const float*)d_in[1];
  const float* b_base   = (const float*)d_in[2];
  const float* lora_A   = (const float*)d_in[3];
  const float* lora_B   = (const float*)d_in[4];
  const float* router_W = (const float*)d_in[5];
  const float* router_b = (const float*)d_in[6];
  const float* prior    = (const float*)d_in[7];
  const int*   active   = (const int*)d_in[8];
  float* out = (float*)d_out;

  const int M = in_sizes[0] / H;  // 8192 tokens

  char* ws = (char*)d_ws;
  _Float16* xh = (_Float16*)ws;                               // M*KP*2  = 68.2 MB
  _Float16* wh = (_Float16*)(ws + (size_t)M * KP * 2);        // O*KP*2  = 34.1 MB
  _Float16* vh = (_Float16*)(ws + (size_t)M * KP * 2 + (size_t)O * KP * 2);  // 384 KB

  convert_w3_kernel<<<O + 48, 256, 0, stream>>>(W_base, lora_B, lora_A, router_W,
                                                active, wh, vh);
  router_fused5_kernel<<<M / 16, 1024, 0, stream>>>(x, vh, router_b, prior, active, xh);
  gemm_kernel<<<(M / BM) * (O / BN), 512, 0, stream>>>(xh, wh, b_base, out);
}